// Round 1
// baseline (1274.720 us; speedup 1.0000x reference)
//
#include <hip/hip_runtime.h>

#define D    768
#define T    16384
#define TQ   8192
#define BINS 1024
#define K1   1536   // conv GEMM K = D*2
#define LPAD 68     // LDS row stride: 16B-aligned for float4, <=2-way bank conflicts

// ---------------------------------------------------------------------------
// cnorm[k] = ||codebook[k]||^2
// ---------------------------------------------------------------------------
__global__ __launch_bounds__(64) void cnorm_kernel(const float* __restrict__ cb,
                                                   float* __restrict__ cnorm) {
    int bin  = blockIdx.x;
    int lane = threadIdx.x;
    const float* row = cb + bin * D;
    float s = 0.f;
    for (int k = lane; k < D; k += 64) { float v = row[k]; s += v * v; }
    #pragma unroll
    for (int off = 32; off > 0; off >>= 1) s += __shfl_down(s, off);
    if (lane == 0) cnorm[bin] = s;
}

// ---------------------------------------------------------------------------
// Conv1d(D,D,k=2,s=2) on batch 0 as GEMM:
//   X2[t'][o] = sum_r W[o][r] * B[r][t'] + bias[o],  r = 2*i+k,
//   B[r][t'] = ssl[i*T + 2*t' + k]  (loaded as float2 pairs)
// M=768 (o), N=8192 (t'), K=1536. 64x64 tile, BK=16, 256 thr, 4x4 micro.
// ---------------------------------------------------------------------------
__global__ __launch_bounds__(256) void conv_gemm_kernel(
    const float* __restrict__ ssl,   // [B, D, T], batch 0 used
    const float* __restrict__ W,     // [D, 1536] row-major
    const float* __restrict__ bias,  // [D]
    float* __restrict__ X2)          // [TQ, D]
{
    __shared__ float As[16 * LPAD];  // As[r][o_local]
    __shared__ float Bs[16 * LPAD];  // Bs[r][t'_local]
    int tid = threadIdx.x;
    int tx = tid & 15, ty = tid >> 4;
    int ob = blockIdx.x * 64;        // o block
    int tb = blockIdx.y * 64;        // t' block

    int a_row = tid >> 2;            // o_local 0..63
    int a_kq  = (tid & 3) << 2;      // 0,4,8,12
    int b_il  = tid >> 6;            // input-channel sub 0..3
    int b_tl  = tid & 63;            // t'_local

    float acc[4][4];                 // acc[j=t'][i=o]
    #pragma unroll
    for (int j = 0; j < 4; ++j)
        #pragma unroll
        for (int i = 0; i < 4; ++i) acc[j][i] = 0.f;

    for (int k0 = 0; k0 < K1; k0 += 16) {
        __syncthreads();
        // A tile: coalesced float4 along K, stored transposed
        float4 av = *(const float4*)&W[(ob + a_row) * K1 + k0 + a_kq];
        As[(a_kq + 0) * LPAD + a_row] = av.x;
        As[(a_kq + 1) * LPAD + a_row] = av.y;
        As[(a_kq + 2) * LPAD + a_row] = av.z;
        As[(a_kq + 3) * LPAD + a_row] = av.w;
        // B tile: float2 covers k=0,1 of one (i, t') pair — fully coalesced
        int i0 = k0 >> 1;
        #pragma unroll
        for (int rep = 0; rep < 2; ++rep) {
            int il = b_il + rep * 4;
            float2 bv = *(const float2*)&ssl[(i0 + il) * T + 2 * (tb + b_tl)];
            Bs[(2 * il + 0) * LPAD + b_tl] = bv.x;
            Bs[(2 * il + 1) * LPAD + b_tl] = bv.y;
        }
        __syncthreads();
        #pragma unroll
        for (int kk = 0; kk < 16; ++kk) {
            float4 a = *(const float4*)&As[kk * LPAD + tx * 4];
            float4 b = *(const float4*)&Bs[kk * LPAD + ty * 4];
            float aa[4] = {a.x, a.y, a.z, a.w};
            float bb[4] = {b.x, b.y, b.z, b.w};
            #pragma unroll
            for (int j = 0; j < 4; ++j)
                #pragma unroll
                for (int i = 0; i < 4; ++i)
                    acc[j][i] += bb[j] * aa[i];
        }
    }
    float4 bv = *(const float4*)&bias[ob + tx * 4];
    float bb[4] = {bv.x, bv.y, bv.z, bv.w};
    #pragma unroll
    for (int j = 0; j < 4; ++j) {
        float4 v = make_float4(acc[j][0] + bb[0], acc[j][1] + bb[1],
                               acc[j][2] + bb[2], acc[j][3] + bb[3]);
        *(float4*)&X2[(tb + ty * 4 + j) * D + ob + tx * 4] = v;  // coalesced
    }
}

// ---------------------------------------------------------------------------
// score[t'][k] = cnorm[k] - 2 * X2[t']·cb[k]; fused argmin over k.
// One block per 64 t' rows; loop 16 bin-tiles of 64; K=768, BK=16.
// Thread (tx,ty): rows = ty*4+i, bins = tx*4+j. Running (min,idx) per row,
// then 16-lane shuffle reduce across tx. Strict < + ascending bins keeps
// the reference lowest-index tie-break.
// ---------------------------------------------------------------------------
__global__ __launch_bounds__(256) void score_kernel(
    const float* __restrict__ X2,     // [TQ, D]
    const float* __restrict__ cb,     // [BINS, D]
    const float* __restrict__ cnorm,  // [BINS]
    int* __restrict__ out)            // [TQ]
{
    __shared__ float As[16 * LPAD];   // As[k][row_local]
    __shared__ float Bs[16 * LPAD];   // Bs[k][bin_local]
    int tid = threadIdx.x;
    int tx = tid & 15, ty = tid >> 4;
    int tb = blockIdx.x * 64;

    int l_row = tid >> 2;             // 0..63
    int l_kq  = (tid & 3) << 2;       // 0,4,8,12

    float minv[4];
    int   mini[4];
    #pragma unroll
    for (int i = 0; i < 4; ++i) { minv[i] = 3.4e38f; mini[i] = 0; }

    for (int nb = 0; nb < BINS; nb += 64) {
        float acc[4][4];              // acc[i=row][j=bin]
        #pragma unroll
        for (int i = 0; i < 4; ++i)
            #pragma unroll
            for (int j = 0; j < 4; ++j) acc[i][j] = 0.f;

        for (int k0 = 0; k0 < D; k0 += 16) {
            __syncthreads();
            float4 av = *(const float4*)&X2[(tb + l_row) * D + k0 + l_kq];
            As[(l_kq + 0) * LPAD + l_row] = av.x;
            As[(l_kq + 1) * LPAD + l_row] = av.y;
            As[(l_kq + 2) * LPAD + l_row] = av.z;
            As[(l_kq + 3) * LPAD + l_row] = av.w;
            float4 bv = *(const float4*)&cb[(nb + l_row) * D + k0 + l_kq];
            Bs[(l_kq + 0) * LPAD + l_row] = bv.x;
            Bs[(l_kq + 1) * LPAD + l_row] = bv.y;
            Bs[(l_kq + 2) * LPAD + l_row] = bv.z;
            Bs[(l_kq + 3) * LPAD + l_row] = bv.w;
            __syncthreads();
            #pragma unroll
            for (int kk = 0; kk < 16; ++kk) {
                float4 a = *(const float4*)&As[kk * LPAD + ty * 4];
                float4 b = *(const float4*)&Bs[kk * LPAD + tx * 4];
                float aa[4] = {a.x, a.y, a.z, a.w};
                float bb[4] = {b.x, b.y, b.z, b.w};
                #pragma unroll
                for (int i = 0; i < 4; ++i)
                    #pragma unroll
                    for (int j = 0; j < 4; ++j)
                        acc[i][j] += aa[i] * bb[j];
            }
        }
        float4 cn4 = *(const float4*)&cnorm[nb + tx * 4];
        float cn[4] = {cn4.x, cn4.y, cn4.z, cn4.w};
        #pragma unroll
        for (int j = 0; j < 4; ++j) {
            int bin = nb + tx * 4 + j;
            #pragma unroll
            for (int i = 0; i < 4; ++i) {
                float s = cn[j] - 2.f * acc[i][j];
                if (s < minv[i]) { minv[i] = s; mini[i] = bin; }
            }
        }
    }
    // reduce (min, idx) across the 16 tx lanes of each ty group (contiguous in wave)
    #pragma unroll
    for (int i = 0; i < 4; ++i) {
        float v = minv[i];
        int   ix = mini[i];
        #pragma unroll
        for (int off = 8; off > 0; off >>= 1) {
            float ov = __shfl_down(v, off);
            int   oi = __shfl_down(ix, off);
            if (ov < v || (ov == v && oi < ix)) { v = ov; ix = oi; }
        }
        minv[i] = v; mini[i] = ix;
    }
    if (tx == 0) {
        #pragma unroll
        for (int i = 0; i < 4; ++i) out[tb + ty * 4 + i] = mini[i];
    }
}

extern "C" void kernel_launch(void* const* d_in, const int* in_sizes, int n_in,
                              void* d_out, int out_size, void* d_ws, size_t ws_size,
                              hipStream_t stream) {
    const float* ssl = (const float*)d_in[0];  // [8, 768, 16384]
    const float* W   = (const float*)d_in[1];  // [768, 768, 2]
    const float* bia = (const float*)d_in[2];  // [768]
    const float* cb  = (const float*)d_in[3];  // [1024, 768]
    int* out = (int*)d_out;                    // [8192] int32 codes

    float* cnorm = (float*)d_ws;               // 1024 floats
    float* X2    = (float*)d_ws + 1024;        // 8192*768 floats (~25 MB)

    cnorm_kernel<<<BINS, 64, 0, stream>>>(cb, cnorm);
    conv_gemm_kernel<<<dim3(D / 64, TQ / 64), 256, 0, stream>>>(ssl, W, bia, X2);
    score_kernel<<<TQ / 64, 256, 0, stream>>>(X2, cb, cnorm, out);
}

// Round 2
// 1023.550 us; speedup vs baseline: 1.2454x; 1.2454x over previous
//
#include <hip/hip_runtime.h>

#define D    768
#define T    16384
#define TQ   8192
#define BINS 1024
#define K1   1536    // conv GEMM K = D*2
#define LPS  132     // LDS row stride for 128-wide tiles (16B-aligned, 2-way max on stores)

// ---------------------------------------------------------------------------
// cnorm[k] = ||codebook[k]||^2
// ---------------------------------------------------------------------------
__global__ __launch_bounds__(64) void cnorm_kernel(const float* __restrict__ cb,
                                                   float* __restrict__ cnorm) {
    int bin  = blockIdx.x;
    int lane = threadIdx.x;
    const float* row = cb + bin * D;
    float s = 0.f;
    for (int k = lane; k < D; k += 64) { float v = row[k]; s += v * v; }
    #pragma unroll
    for (int off = 32; off > 0; off >>= 1) s += __shfl_down(s, off);
    if (lane == 0) cnorm[bin] = s;
}

// ---------------------------------------------------------------------------
// Conv1d(D,D,k=2,s=2) on batch 0 as GEMM: X2[t'][o] = sum_r W[o][r]*B[r][t'] + bias[o]
// r = 2*i+k, B[r][t'] = ssl[i*T + 2*t' + k] (coalesced float2 loads).
// M=768, N=8192, K=1536. 128x128 tile, BK=16, 256 thr, 8x8 micro.
// ---------------------------------------------------------------------------
__global__ __launch_bounds__(256, 2) void conv_gemm_kernel(
    const float* __restrict__ ssl,   // [B, D, T], batch 0 used
    const float* __restrict__ W,     // [D, 1536] row-major
    const float* __restrict__ bias,  // [D]
    float* __restrict__ X2)          // [TQ, D]
{
    __shared__ float As[16 * LPS];   // As[r][o_local 0..127]
    __shared__ float Bs[16 * LPS];   // Bs[r][t'_local 0..127]
    int tid = threadIdx.x;
    int tx = tid & 15, ty = tid >> 4;   // tx -> o (8 each), ty -> t' (8 each)
    int ob = blockIdx.x * 128;
    int tb = blockIdx.y * 128;

    float acc[8][8];                 // acc[j=t'][i=o]
    #pragma unroll
    for (int j = 0; j < 8; ++j)
        #pragma unroll
        for (int i = 0; i < 8; ++i) acc[j][i] = 0.f;

    for (int k0 = 0; k0 < K1; k0 += 16) {
        __syncthreads();
        // A tile: 128 o x 16 k = 512 float4; 2 per thread
        #pragma unroll
        for (int rep = 0; rep < 2; ++rep) {
            int l = tid + 256 * rep;
            int o_l = l >> 2, kq = (l & 3) << 2;
            float4 v = *(const float4*)&W[(ob + o_l) * K1 + k0 + kq];
            As[(kq + 0) * LPS + o_l] = v.x;
            As[(kq + 1) * LPS + o_l] = v.y;
            As[(kq + 2) * LPS + o_l] = v.z;
            As[(kq + 3) * LPS + o_l] = v.w;
        }
        // B tile: 8 in-ch x 128 t' float2 pairs = 1024; 4 per thread
        int i0 = k0 >> 1;
        #pragma unroll
        for (int rep = 0; rep < 4; ++rep) {
            int l = tid + 256 * rep;
            int i_l = l >> 7, t_l = l & 127;
            float2 bv = *(const float2*)&ssl[(i0 + i_l) * T + 2 * (tb + t_l)];
            Bs[(2 * i_l + 0) * LPS + t_l] = bv.x;
            Bs[(2 * i_l + 1) * LPS + t_l] = bv.y;
        }
        __syncthreads();
        #pragma unroll 4
        for (int kk = 0; kk < 16; ++kk) {
            float4 a0 = *(const float4*)&As[kk * LPS + tx * 8];
            float4 a1 = *(const float4*)&As[kk * LPS + tx * 8 + 4];
            float4 b0 = *(const float4*)&Bs[kk * LPS + ty * 8];
            float4 b1 = *(const float4*)&Bs[kk * LPS + ty * 8 + 4];
            float aa[8] = {a0.x, a0.y, a0.z, a0.w, a1.x, a1.y, a1.z, a1.w};
            float bb[8] = {b0.x, b0.y, b0.z, b0.w, b1.x, b1.y, b1.z, b1.w};
            #pragma unroll
            for (int j = 0; j < 8; ++j)
                #pragma unroll
                for (int i = 0; i < 8; ++i)
                    acc[j][i] += bb[j] * aa[i];
        }
    }
    float4 bv0 = *(const float4*)&bias[ob + tx * 8];
    float4 bv1 = *(const float4*)&bias[ob + tx * 8 + 4];
    float bb[8] = {bv0.x, bv0.y, bv0.z, bv0.w, bv1.x, bv1.y, bv1.z, bv1.w};
    #pragma unroll
    for (int j = 0; j < 8; ++j) {
        float* dst = &X2[(tb + ty * 8 + j) * D + ob + tx * 8];
        float4 v0 = make_float4(acc[j][0] + bb[0], acc[j][1] + bb[1],
                                acc[j][2] + bb[2], acc[j][3] + bb[3]);
        float4 v1 = make_float4(acc[j][4] + bb[4], acc[j][5] + bb[5],
                                acc[j][6] + bb[6], acc[j][7] + bb[7]);
        *(float4*)dst = v0;
        *(float4*)(dst + 4) = v1;
    }
}

// ---------------------------------------------------------------------------
// Fused distance+partial-argmin: block = 128 rows x one 128-bin slice.
// Grid: (TQ/128 = 64) x (BINS/128 = 8) = 512 blocks.
// Writes (minval, minidx) per (row, slice) to workspace; strict < keeps
// lowest-bin tie-break within the slice.
// ---------------------------------------------------------------------------
__global__ __launch_bounds__(256, 2) void score_kernel(
    const float* __restrict__ X2,     // [TQ, D]
    const float* __restrict__ cb,     // [BINS, D]
    const float* __restrict__ cnorm,  // [BINS]
    float* __restrict__ pval,         // [TQ, 8]
    int* __restrict__ pidx)           // [TQ, 8]
{
    __shared__ float As[16 * LPS];    // As[k][row_local 0..127]
    __shared__ float Bs[16 * LPS];    // Bs[k][bin_local 0..127]
    int tid = threadIdx.x;
    int tx = tid & 15, ty = tid >> 4; // tx -> bins (8), ty -> rows (8)
    int rb = blockIdx.x * 128;
    int sb = blockIdx.y;              // slice index 0..7
    int nb0 = sb * 128;

    float acc[8][8];                  // acc[i=row][j=bin] = x.c
    #pragma unroll
    for (int i = 0; i < 8; ++i)
        #pragma unroll
        for (int j = 0; j < 8; ++j) acc[i][j] = 0.f;

    for (int k0 = 0; k0 < D; k0 += 16) {
        __syncthreads();
        #pragma unroll
        for (int rep = 0; rep < 2; ++rep) {
            int l = tid + 256 * rep;
            int r_l = l >> 2, kq = (l & 3) << 2;
            float4 v = *(const float4*)&X2[(rb + r_l) * D + k0 + kq];
            As[(kq + 0) * LPS + r_l] = v.x;
            As[(kq + 1) * LPS + r_l] = v.y;
            As[(kq + 2) * LPS + r_l] = v.z;
            As[(kq + 3) * LPS + r_l] = v.w;
            float4 w = *(const float4*)&cb[(nb0 + r_l) * D + k0 + kq];
            Bs[(kq + 0) * LPS + r_l] = w.x;
            Bs[(kq + 1) * LPS + r_l] = w.y;
            Bs[(kq + 2) * LPS + r_l] = w.z;
            Bs[(kq + 3) * LPS + r_l] = w.w;
        }
        __syncthreads();
        #pragma unroll 4
        for (int kk = 0; kk < 16; ++kk) {
            float4 a0 = *(const float4*)&As[kk * LPS + ty * 8];
            float4 a1 = *(const float4*)&As[kk * LPS + ty * 8 + 4];
            float4 b0 = *(const float4*)&Bs[kk * LPS + tx * 8];
            float4 b1 = *(const float4*)&Bs[kk * LPS + tx * 8 + 4];
            float aa[8] = {a0.x, a0.y, a0.z, a0.w, a1.x, a1.y, a1.z, a1.w};
            float bb[8] = {b0.x, b0.y, b0.z, b0.w, b1.x, b1.y, b1.z, b1.w};
            #pragma unroll
            for (int i = 0; i < 8; ++i)
                #pragma unroll
                for (int j = 0; j < 8; ++j)
                    acc[i][j] += aa[i] * bb[j];
        }
    }
    // epilogue: s = cnorm[bin] - 2*dot ; running argmin per row
    float4 c0 = *(const float4*)&cnorm[nb0 + tx * 8];
    float4 c1 = *(const float4*)&cnorm[nb0 + tx * 8 + 4];
    float cn[8] = {c0.x, c0.y, c0.z, c0.w, c1.x, c1.y, c1.z, c1.w};
    float minv[8];
    int   mini[8];
    #pragma unroll
    for (int i = 0; i < 8; ++i) {
        float v = 3.4e38f; int ix = 0;
        #pragma unroll
        for (int j = 0; j < 8; ++j) {
            float s = cn[j] - 2.f * acc[i][j];
            int bin = nb0 + tx * 8 + j;
            if (s < v) { v = s; ix = bin; }
        }
        minv[i] = v; mini[i] = ix;
    }
    // reduce across the 16 tx lanes (contiguous within wave)
    #pragma unroll
    for (int i = 0; i < 8; ++i) {
        float v = minv[i];
        int   ix = mini[i];
        #pragma unroll
        for (int off = 8; off > 0; off >>= 1) {
            float ov = __shfl_down(v, off);
            int   oi = __shfl_down(ix, off);
            if (ov < v || (ov == v && oi < ix)) { v = ov; ix = oi; }
        }
        minv[i] = v; mini[i] = ix;
    }
    if (tx == 0) {
        #pragma unroll
        for (int i = 0; i < 8; ++i) {
            int r = rb + ty * 8 + i;
            pval[r * 8 + sb] = minv[i];
            pidx[r * 8 + sb] = mini[i];
        }
    }
}

// ---------------------------------------------------------------------------
// Final reduce over the 8 bin-slices. Ascending slice = ascending bins, so
// strict < keeps the reference's lowest-index tie-break.
// ---------------------------------------------------------------------------
__global__ __launch_bounds__(256) void argmin_final_kernel(
    const float* __restrict__ pval, const int* __restrict__ pidx,
    int* __restrict__ out)
{
    int r = blockIdx.x * 256 + threadIdx.x;
    float best = 3.4e38f; int bi = 0;
    #pragma unroll
    for (int s = 0; s < 8; ++s) {
        float v = pval[r * 8 + s];
        int   i = pidx[r * 8 + s];
        if (v < best) { best = v; bi = i; }
    }
    out[r] = bi;
}

extern "C" void kernel_launch(void* const* d_in, const int* in_sizes, int n_in,
                              void* d_out, int out_size, void* d_ws, size_t ws_size,
                              hipStream_t stream) {
    const float* ssl = (const float*)d_in[0];  // [8, 768, 16384]
    const float* W   = (const float*)d_in[1];  // [768, 768, 2]
    const float* bia = (const float*)d_in[2];  // [768]
    const float* cb  = (const float*)d_in[3];  // [1024, 768]
    int* out = (int*)d_out;                    // [8192] int32 codes

    float* cnorm = (float*)d_ws;                       // 1024 floats
    float* X2    = cnorm + 1024;                       // 8192*768 floats (~25 MB)
    float* pval  = X2 + (size_t)TQ * D;                // 8192*8 floats
    int*   pidx  = (int*)(pval + (size_t)TQ * 8);      // 8192*8 ints

    cnorm_kernel<<<BINS, 64, 0, stream>>>(cb, cnorm);
    conv_gemm_kernel<<<dim3(D / 128, TQ / 128), 256, 0, stream>>>(ssl, W, bia, X2);
    score_kernel<<<dim3(TQ / 128, BINS / 128), 256, 0, stream>>>(X2, cb, cnorm, pval, pidx);
    argmin_final_kernel<<<TQ / 256, 256, 0, stream>>>(pval, pidx, out);
}

// Round 3
// 840.539 us; speedup vs baseline: 1.5166x; 1.2177x over previous
//
#include <hip/hip_runtime.h>

#define D    768
#define T    16384
#define TQ   8192
#define BINS 1024
#define K1   1536    // conv GEMM K = D*2
#define LPS  132     // LDS row stride, 128-wide tiles (16B-aligned)
#define LPA  68      // LDS row stride, 64-wide tiles

// ---------------------------------------------------------------------------
// cnorm[k] = ||codebook[k]||^2
// ---------------------------------------------------------------------------
__global__ __launch_bounds__(64) void cnorm_kernel(const float* __restrict__ cb,
                                                   float* __restrict__ cnorm) {
    int bin  = blockIdx.x;
    int lane = threadIdx.x;
    const float* row = cb + bin * D;
    float s = 0.f;
    for (int k = lane; k < D; k += 64) { float v = row[k]; s += v * v; }
    #pragma unroll
    for (int off = 32; off > 0; off >>= 1) s += __shfl_down(s, off);
    if (lane == 0) cnorm[bin] = s;
}

// ---------------------------------------------------------------------------
// Conv1d(D,D,k=2,s=2) batch 0 as GEMM, split-K over blockIdx.z.
// X_part[t'][o] = sum_{r in half} W[o][r]*B[r][t']   (bias folded later,
// unless `bias` non-null in the single-pass fallback).
// 128x128 tile, BK=16, 256 thr, 8x8 micro as TWO contiguous float4 groups
// per dim (stride-16B LDS reads -> 2-way bank aliasing = free).
// ---------------------------------------------------------------------------
__global__ __launch_bounds__(256, 3) void conv_gemm_kernel(
    const float* __restrict__ ssl,   // [B, D, T], batch 0 used
    const float* __restrict__ W,     // [D, 1536] row-major
    const float* __restrict__ bias,  // null in split mode
    float* __restrict__ dst0,        // partial for z=0 (or full X2 in fallback)
    float* __restrict__ dst1,        // partial for z=1
    int kbase_mult, int klen)
{
    __shared__ float As[16 * LPS];   // As[r][o_local 0..127]
    __shared__ float Bs[16 * LPS];   // Bs[r][t'_local 0..127]
    int tid = threadIdx.x;
    int tx = tid & 15, ty = tid >> 4;
    int ob = blockIdx.x * 128;
    int tb = blockIdx.y * 128;
    int kh = blockIdx.z;
    int kbeg = kh * kbase_mult;
    float* __restrict__ dst = kh ? dst1 : dst0;

    float acc[8][8];                 // acc[j=t'][i=o]
    #pragma unroll
    for (int j = 0; j < 8; ++j)
        #pragma unroll
        for (int i = 0; i < 8; ++i) acc[j][i] = 0.f;

    for (int k0 = kbeg; k0 < kbeg + klen; k0 += 16) {
        __syncthreads();
        // A tile: 128 o x 16 k = 512 float4; 2 per thread
        #pragma unroll
        for (int rep = 0; rep < 2; ++rep) {
            int l = tid + 256 * rep;
            int o_l = l >> 2, kq = (l & 3) << 2;
            float4 v = *(const float4*)&W[(ob + o_l) * K1 + k0 + kq];
            As[(kq + 0) * LPS + o_l] = v.x;
            As[(kq + 1) * LPS + o_l] = v.y;
            As[(kq + 2) * LPS + o_l] = v.z;
            As[(kq + 3) * LPS + o_l] = v.w;
        }
        // B tile: 8 in-ch x 128 t' float2 pairs; 4 per thread
        int i0 = k0 >> 1;
        #pragma unroll
        for (int rep = 0; rep < 4; ++rep) {
            int l = tid + 256 * rep;
            int i_l = l >> 7, t_l = l & 127;
            float2 bv = *(const float2*)&ssl[(i0 + i_l) * T + 2 * (tb + t_l)];
            Bs[(2 * i_l + 0) * LPS + t_l] = bv.x;
            Bs[(2 * i_l + 1) * LPS + t_l] = bv.y;
        }
        __syncthreads();
        #pragma unroll 4
        for (int kk = 0; kk < 16; ++kk) {
            float4 a0 = *(const float4*)&As[kk * LPS + tx * 4];
            float4 a1 = *(const float4*)&As[kk * LPS + 64 + tx * 4];
            float4 b0 = *(const float4*)&Bs[kk * LPS + ty * 4];
            float4 b1 = *(const float4*)&Bs[kk * LPS + 64 + ty * 4];
            float aa[8] = {a0.x, a0.y, a0.z, a0.w, a1.x, a1.y, a1.z, a1.w};
            float bb[8] = {b0.x, b0.y, b0.z, b0.w, b1.x, b1.y, b1.z, b1.w};
            #pragma unroll
            for (int j = 0; j < 8; ++j)
                #pragma unroll
                for (int i = 0; i < 8; ++i)
                    acc[j][i] += bb[j] * aa[i];
        }
    }
    float bb[8] = {0,0,0,0,0,0,0,0};
    if (bias) {
        float4 bv0 = *(const float4*)&bias[ob + tx * 4];
        float4 bv1 = *(const float4*)&bias[ob + 64 + tx * 4];
        bb[0]=bv0.x; bb[1]=bv0.y; bb[2]=bv0.z; bb[3]=bv0.w;
        bb[4]=bv1.x; bb[5]=bv1.y; bb[6]=bv1.z; bb[7]=bv1.w;
    }
    #pragma unroll
    for (int j = 0; j < 8; ++j) {
        int tp = tb + (j < 4 ? ty * 4 + j : 64 + ty * 4 + (j - 4));
        float4 v0 = make_float4(acc[j][0] + bb[0], acc[j][1] + bb[1],
                                acc[j][2] + bb[2], acc[j][3] + bb[3]);
        float4 v1 = make_float4(acc[j][4] + bb[4], acc[j][5] + bb[5],
                                acc[j][6] + bb[6], acc[j][7] + bb[7]);
        *(float4*)&dst[tp * D + ob + tx * 4] = v0;
        *(float4*)&dst[tp * D + ob + 64 + tx * 4] = v1;
    }
}

// ---------------------------------------------------------------------------
// X2 = P0 + P1 + bias (in place into P0's buffer)
// ---------------------------------------------------------------------------
__global__ __launch_bounds__(256) void combine_kernel(
    float* __restrict__ X2, const float* __restrict__ P1,
    const float* __restrict__ bias)
{
    int i4 = blockIdx.x * 256 + threadIdx.x;   // float4 index, TQ*D/4 total
    int o = (i4 * 4) % D;
    float4 a = *(const float4*)&X2[i4 * 4];
    float4 b = *(const float4*)&P1[i4 * 4];
    float4 c = *(const float4*)&bias[o];
    float4 r = make_float4(a.x + b.x + c.x, a.y + b.y + c.y,
                           a.z + b.z + c.z, a.w + b.w + c.w);
    *(float4*)&X2[i4 * 4] = r;
}

// ---------------------------------------------------------------------------
// Fused distance + partial argmin. Block = 64 rows x 128-bin slice.
// Grid: (TQ/64 = 128) x (BINS/128 = 8) = 1024 blocks (4/CU).
// Micro: 4 rows (one float4 at ty*4) x 8 bins (two float4 groups tx*4,
// 64+tx*4) -> all LDS reads stride-16B (free 2-way).
// ---------------------------------------------------------------------------
__global__ __launch_bounds__(256, 4) void score_kernel(
    const float* __restrict__ X2,     // [TQ, D]
    const float* __restrict__ cb,     // [BINS, D]
    const float* __restrict__ cnorm,  // [BINS]
    float* __restrict__ pval,         // [TQ, 8]
    int* __restrict__ pidx)           // [TQ, 8]
{
    __shared__ float As[16 * LPA];    // As[k][row_local 0..63]
    __shared__ float Bs[16 * LPS];    // Bs[k][bin_local 0..127]
    int tid = threadIdx.x;
    int tx = tid & 15, ty = tid >> 4; // tx -> bins, ty -> rows
    int rb = blockIdx.x * 64;
    int sb = blockIdx.y;
    int nb0 = sb * 128;

    float acc[4][8];                  // acc[i=row][j=bin]
    #pragma unroll
    for (int i = 0; i < 4; ++i)
        #pragma unroll
        for (int j = 0; j < 8; ++j) acc[i][j] = 0.f;

    for (int k0 = 0; k0 < D; k0 += 16) {
        __syncthreads();
        {   // A tile: 64 rows x 16 k = 256 float4; 1 per thread
            int r_l = tid >> 2, kq = (tid & 3) << 2;
            float4 v = *(const float4*)&X2[(rb + r_l) * D + k0 + kq];
            As[(kq + 0) * LPA + r_l] = v.x;
            As[(kq + 1) * LPA + r_l] = v.y;
            As[(kq + 2) * LPA + r_l] = v.z;
            As[(kq + 3) * LPA + r_l] = v.w;
        }
        #pragma unroll
        for (int rep = 0; rep < 2; ++rep) {  // B tile: 128 bins x 16 k
            int l = tid + 256 * rep;
            int b_l = l >> 2, kq = (l & 3) << 2;
            float4 v = *(const float4*)&cb[(nb0 + b_l) * D + k0 + kq];
            Bs[(kq + 0) * LPS + b_l] = v.x;
            Bs[(kq + 1) * LPS + b_l] = v.y;
            Bs[(kq + 2) * LPS + b_l] = v.z;
            Bs[(kq + 3) * LPS + b_l] = v.w;
        }
        __syncthreads();
        #pragma unroll 4
        for (int kk = 0; kk < 16; ++kk) {
            float4 a  = *(const float4*)&As[kk * LPA + ty * 4];
            float4 b0 = *(const float4*)&Bs[kk * LPS + tx * 4];
            float4 b1 = *(const float4*)&Bs[kk * LPS + 64 + tx * 4];
            float aa[4] = {a.x, a.y, a.z, a.w};
            float bb[8] = {b0.x, b0.y, b0.z, b0.w, b1.x, b1.y, b1.z, b1.w};
            #pragma unroll
            for (int i = 0; i < 4; ++i)
                #pragma unroll
                for (int j = 0; j < 8; ++j)
                    acc[i][j] += aa[i] * bb[j];
        }
    }
    // epilogue: s = cnorm[bin] - 2*dot; per-row running argmin (bins ascend)
    float4 c0 = *(const float4*)&cnorm[nb0 + tx * 4];
    float4 c1 = *(const float4*)&cnorm[nb0 + 64 + tx * 4];
    float cn[8] = {c0.x, c0.y, c0.z, c0.w, c1.x, c1.y, c1.z, c1.w};
    #pragma unroll
    for (int i = 0; i < 4; ++i) {
        float v = 3.4e38f; int ix = 0;
        #pragma unroll
        for (int j = 0; j < 8; ++j) {
            float s = cn[j] - 2.f * acc[i][j];
            int bin = nb0 + (j < 4 ? tx * 4 + j : 64 + tx * 4 + (j - 4));
            if (s < v) { v = s; ix = bin; }
        }
        // reduce across the 16 tx lanes (contiguous within wave)
        #pragma unroll
        for (int off = 8; off > 0; off >>= 1) {
            float ov = __shfl_down(v, off);
            int   oi = __shfl_down(ix, off);
            if (ov < v || (ov == v && oi < ix)) { v = ov; ix = oi; }
        }
        if (tx == 0) {
            int r = rb + ty * 4 + i;
            pval[r * 8 + sb] = v;
            pidx[r * 8 + sb] = ix;
        }
    }
}

// ---------------------------------------------------------------------------
// Final reduce over the 8 bin-slices (ascending slices keep tie-break).
// ---------------------------------------------------------------------------
__global__ __launch_bounds__(256) void argmin_final_kernel(
    const float* __restrict__ pval, const int* __restrict__ pidx,
    int* __restrict__ out)
{
    int r = blockIdx.x * 256 + threadIdx.x;
    float best = 3.4e38f; int bi = 0;
    #pragma unroll
    for (int s = 0; s < 8; ++s) {
        float v = pval[r * 8 + s];
        int   i = pidx[r * 8 + s];
        if (v < best) { best = v; bi = i; }
    }
    out[r] = bi;
}

extern "C" void kernel_launch(void* const* d_in, const int* in_sizes, int n_in,
                              void* d_out, int out_size, void* d_ws, size_t ws_size,
                              hipStream_t stream) {
    const float* ssl = (const float*)d_in[0];  // [8, 768, 16384]
    const float* W   = (const float*)d_in[1];  // [768, 768, 2]
    const float* bia = (const float*)d_in[2];  // [768]
    const float* cb  = (const float*)d_in[3];  // [1024, 768]
    int* out = (int*)d_out;                    // [8192] int32 codes

    float* cnorm = (float*)d_ws;                       // 1024 floats
    float* X2    = cnorm + 1024;                       // TQ*D floats (25 MB)
    float* P1    = X2 + (size_t)TQ * D;                // TQ*D floats (25 MB, split-K)
    float* pval_s  = P1 + (size_t)TQ * D;              // TQ*8
    int*   pidx_s  = (int*)(pval_s + (size_t)TQ * 8);
    size_t need_split = (size_t)(1024 + 2 * TQ * D + TQ * 16) * 4;

    cnorm_kernel<<<BINS, 64, 0, stream>>>(cb, cnorm);

    float* pval; int* pidx;
    if (ws_size >= need_split) {
        // split-K x2: 768 blocks (3/CU); bias folded in combine
        conv_gemm_kernel<<<dim3(D / 128, TQ / 128, 2), 256, 0, stream>>>(
            ssl, W, nullptr, X2, P1, K1 / 2, K1 / 2);
        combine_kernel<<<(TQ * D / 4) / 256, 256, 0, stream>>>(X2, P1, bia);
        pval = pval_s; pidx = pidx_s;
    } else {
        // fallback: single pass over full K, bias in epilogue
        conv_gemm_kernel<<<dim3(D / 128, TQ / 128, 1), 256, 0, stream>>>(
            ssl, W, bia, X2, nullptr, 0, K1);
        pval = X2 + (size_t)TQ * D;
        pidx = (int*)(pval + (size_t)TQ * 8);
    }

    score_kernel<<<dim3(TQ / 64, BINS / 128), 256, 0, stream>>>(X2, cb, cnorm, pval, pidx);
    argmin_final_kernel<<<TQ / 256, 256, 0, stream>>>(pval, pidx, out);
}